// Round 3
// baseline (1493.213 us; speedup 1.0000x reference)
//
#include <hip/hip_runtime.h>

#define DEV __device__ __forceinline__

typedef __attribute__((ext_vector_type(8))) short s8v;
typedef __attribute__((ext_vector_type(4))) short s4v;
typedef __attribute__((ext_vector_type(4))) float f4v;

#define BB 2
#define SS 2048
#define EE 1024
#define AA 1024
#define HH 16
#define FF 4096
#define LL 4
#define DHD 64
#define MM (BB*SS)   /* 4096 rows */

DEV float b2f(short s){
  union { unsigned int u; float f; } v; v.u = ((unsigned int)(unsigned short)s) << 16; return v.f;
}
DEV short f2b(float f){
  unsigned int u = __float_as_uint(f);
  unsigned int r = (u + 0x7FFFu + ((u >> 16) & 1u)) >> 16;
  return (short)(unsigned short)r;
}
DEV f4v fzero(){ f4v v; v[0]=0.f; v[1]=0.f; v[2]=0.f; v[3]=0.f; return v; }

// ---------------- add positional encoding: xres(f32) = x + pe ; xb = bf16 ----------------
__global__ __launch_bounds__(256) void add_pe_k(const float* __restrict__ x, const float* __restrict__ pe,
                                                float* __restrict__ xres, short* __restrict__ xb){
  size_t g = ((size_t)blockIdx.x*256 + threadIdx.x) * 4;
  f4v xv = *(const f4v*)(x + g);
  f4v pv = *(const f4v*)(pe + (g & (size_t)(SS*EE - 1)));
  f4v ov; s4v ob;
  #pragma unroll
  for (int j=0;j<4;j++){ float f = xv[j] + pv[j]; ov[j]=f; ob[j]=f2b(f); }
  *(f4v*)(xres + g) = ov;
  *(s4v*)(xb + g) = ob;
}

// ---------------- batched transpose+convert: in[z][R][C] (f32) -> out[z][C][R] (bf16) ----------------
__global__ __launch_bounds__(256) void transpose_f2b(const float* __restrict__ in, short* __restrict__ out,
                                                     int R, int C){
  __shared__ short t[32][33];
  int tx = threadIdx.x, ty = threadIdx.y;
  int rt = blockIdx.y*32, ct = blockIdx.x*32;
  size_t zb = (size_t)blockIdx.z * R * C;
  #pragma unroll
  for (int yy=0; yy<4; yy++){
    int iy = ty + yy*8;
    t[iy][tx] = f2b(in[zb + (size_t)(rt+iy)*C + ct + tx]);
  }
  __syncthreads();
  #pragma unroll
  for (int yy=0; yy<4; yy++){
    int iy = ty + yy*8;
    out[zb + (size_t)(ct+iy)*R + rt + tx] = t[tx][iy];
  }
}

// ---------------- concat per-layer qkv biases into [3A] (f32) ----------------
__global__ void concat_bias(const float* __restrict__ bq, const float* __restrict__ bk,
                            const float* __restrict__ bv, float* __restrict__ out){
  int i = blockIdx.x*256 + threadIdx.x;
  float v = (i < AA) ? bq[i] : (i < 2*AA ? bk[i-AA] : bv[i-2*AA]);
  out[i] = v;
}

// ---------------- GEMM: C[M,N] = A[M,K](bf16) * Bt[N,K]^T + bias(f32) ----------------
// OUTMODE: 0 = bf16, 1 = bf16 + relu
// Register-staged LDS fill (global -> VGPR -> ds_write_b128): correctness-first.
template<int BM, int BN, int OUTMODE>
__global__ __launch_bounds__(256) void gemm_bt(const short* __restrict__ Ag, const short* __restrict__ Btg,
                                               const float* __restrict__ bias, short* __restrict__ Cout,
                                               int M, int N, int K){
  constexpr int WM = BM/2, WN = BN/2;
  constexpr int MI = WM/16, NI = WN/16;
  constexpr int ACH = BM/16, BCH = BN/16, TCH = ACH + BCH, CPW = TCH/4;
  __shared__ __attribute__((aligned(16))) short As[BM*32];
  __shared__ __attribute__((aligned(16))) short Bs[BN*32];
  const int tid = threadIdx.x;
  const int wave = tid >> 6, lane = tid & 63;
  const int wr = wave >> 1, wc = wave & 1;
  const int l15 = lane & 15, l4 = lane >> 4;
  const int bm = blockIdx.y * BM, bn = blockIdx.x * BN;
  const int lrow = lane >> 2, lcol = (lane & 3) * 8;

  f4v acc[MI][NI];
  #pragma unroll
  for (int i=0;i<MI;i++)
    #pragma unroll
    for (int j=0;j<NI;j++) acc[i][j] = fzero();

  for (int kt = 0; kt < K; kt += 32){
    s8v stg[CPW];
    #pragma unroll
    for (int c = 0; c < CPW; c++){
      int ch = wave * CPW + c;
      if (ch < ACH){
        int r = ch*16 + lrow;
        stg[c] = *(const s8v*)(Ag + (size_t)(bm + r)*K + kt + lcol);
      } else {
        int r = (ch-ACH)*16 + lrow;
        stg[c] = *(const s8v*)(Btg + (size_t)(bn + r)*K + kt + lcol);
      }
    }
    #pragma unroll
    for (int c = 0; c < CPW; c++){
      int ch = wave * CPW + c;
      if (ch < ACH) *(s8v*)&As[ch*512 + lane*8] = stg[c];
      else          *(s8v*)&Bs[(ch-ACH)*512 + lane*8] = stg[c];
    }
    __syncthreads();
    s8v af[MI], bfr[NI];
    #pragma unroll
    for (int mi=0;mi<MI;mi++) af[mi] = *(const s8v*)&As[(wr*WM + mi*16 + l15)*32 + l4*8];
    #pragma unroll
    for (int ni=0;ni<NI;ni++) bfr[ni] = *(const s8v*)&Bs[(wc*WN + ni*16 + l15)*32 + l4*8];
    #pragma unroll
    for (int mi=0;mi<MI;mi++)
      #pragma unroll
      for (int ni=0;ni<NI;ni++)
        acc[mi][ni] = __builtin_amdgcn_mfma_f32_16x16x32_bf16(af[mi], bfr[ni], acc[mi][ni], 0,0,0);
    __syncthreads();
  }
  #pragma unroll
  for (int mi=0;mi<MI;mi++){
    int row = bm + wr*WM + mi*16 + l4*4;
    #pragma unroll
    for (int ni=0;ni<NI;ni++){
      int col = bn + wc*WN + ni*16 + l15;
      float bv = bias[col];
      #pragma unroll
      for (int r=0;r<4;r++){
        float v = acc[mi][ni][r] + bv;
        if constexpr (OUTMODE==1) v = fmaxf(v, 0.f);
        Cout[(size_t)(row+r)*N + col] = f2b(v);
      }
    }
  }
}

// ---------------- flash attention: qkv[M][3A](bf16) -> o[M][A](bf16) ----------------
__global__ __launch_bounds__(256) void attn_k(const short* __restrict__ qkv, short* __restrict__ o){
  __shared__ __attribute__((aligned(16))) short Kls[64][72];
  __shared__ __attribute__((aligned(16))) short Vls[64][72];
  __shared__ __attribute__((aligned(16))) short Pls[4][16][72];
  const int tid = threadIdx.x, wave = tid>>6, lane = tid&63;
  const int l15 = lane&15, l4 = lane>>4;
  const int qb = blockIdx.x, bh = blockIdx.y;
  const int b = bh >> 4, h = bh & 15;
  const size_t rs = 3*AA;
  const short* qbase = qkv + (size_t)b*SS*rs + h*64;
  const short* kbase = qbase + AA;
  const short* vbase = qbase + 2*AA;
  const int m0 = qb*64 + wave*16;

  s8v aq0 = *(const s8v*)(qbase + (size_t)(m0 + l15)*rs + l4*8);
  s8v aq1 = *(const s8v*)(qbase + (size_t)(m0 + l15)*rs + 32 + l4*8);

  f4v oacc[4];
  #pragma unroll
  for (int df=0;df<4;df++) oacc[df] = fzero();
  float mrow[4] = {-1e30f,-1e30f,-1e30f,-1e30f};
  float lrow[4] = {0.f,0.f,0.f,0.f};

  const int srow = tid>>2, scol = (tid&3)*16;
  for (int t0=0; t0<SS; t0+=64){
    const short* kr = kbase + (size_t)(t0+srow)*rs + scol;
    *(s8v*)&Kls[srow][scol]   = *(const s8v*)kr;
    *(s8v*)&Kls[srow][scol+8] = *(const s8v*)(kr+8);
    const short* vr = vbase + (size_t)(t0+srow)*rs + scol;
    s8v v0 = *(const s8v*)vr;
    s8v v1 = *(const s8v*)(vr+8);
    #pragma unroll
    for (int j=0;j<8;j++){ Vls[scol+j][srow] = v0[j]; Vls[scol+8+j][srow] = v1[j]; }
    __syncthreads();

    f4v sacc[4];
    #pragma unroll
    for (int f=0;f<4;f++) sacc[f] = fzero();
    #pragma unroll
    for (int f=0; f<4; f++){
      s8v k0 = *(const s8v*)&Kls[f*16+l15][l4*8];
      s8v k1 = *(const s8v*)&Kls[f*16+l15][32+l4*8];
      sacc[f] = __builtin_amdgcn_mfma_f32_16x16x32_bf16(aq0, k0, sacc[f], 0,0,0);
      sacc[f] = __builtin_amdgcn_mfma_f32_16x16x32_bf16(aq1, k1, sacc[f], 0,0,0);
    }
    #pragma unroll
    for (int f=0;f<4;f++) sacc[f] = sacc[f] * 0.125f;

    float fac[4];
    #pragma unroll
    for (int r=0;r<4;r++){
      float mx = fmaxf(fmaxf(sacc[0][r], sacc[1][r]), fmaxf(sacc[2][r], sacc[3][r]));
      #pragma unroll
      for (int msk=1; msk<16; msk<<=1) mx = fmaxf(mx, __shfl_xor(mx, msk));
      float mnew = fmaxf(mrow[r], mx);
      float fc = __expf(mrow[r] - mnew);
      mrow[r] = mnew; fac[r] = fc;
      float rsum = 0.f;
      #pragma unroll
      for (int f=0;f<4;f++){
        float p = __expf(sacc[f][r] - mnew);
        sacc[f][r] = p; rsum += p;
      }
      #pragma unroll
      for (int msk=1; msk<16; msk<<=1) rsum += __shfl_xor(rsum, msk);
      lrow[r] = lrow[r]*fc + rsum;
    }
    f4v fv; fv[0]=fac[0]; fv[1]=fac[1]; fv[2]=fac[2]; fv[3]=fac[3];
    #pragma unroll
    for (int df=0;df<4;df++) oacc[df] = oacc[df] * fv;

    #pragma unroll
    for (int f=0;f<4;f++)
      #pragma unroll
      for (int r=0;r<4;r++)
        Pls[wave][l4*4+r][f*16+l15] = f2b(sacc[f][r]);

    s8v ap0 = *(const s8v*)&Pls[wave][l15][l4*8];
    s8v ap1 = *(const s8v*)&Pls[wave][l15][32+l4*8];
    #pragma unroll
    for (int df=0;df<4;df++){
      s8v bv0 = *(const s8v*)&Vls[df*16+l15][l4*8];
      s8v bv1 = *(const s8v*)&Vls[df*16+l15][32+l4*8];
      oacc[df] = __builtin_amdgcn_mfma_f32_16x16x32_bf16(ap0, bv0, oacc[df], 0,0,0);
      oacc[df] = __builtin_amdgcn_mfma_f32_16x16x32_bf16(ap1, bv1, oacc[df], 0,0,0);
    }
    __syncthreads();
  }
  #pragma unroll
  for (int df=0;df<4;df++)
    #pragma unroll
    for (int r=0;r<4;r++){
      float v = oacc[df][r] / lrow[r];
      o[(size_t)(b*SS + m0 + l4*4 + r)*AA + h*64 + df*16 + l15] = f2b(v);
    }
}

// ---------------- fused residual + layernorm: y = LN(b2f(y1)+y2); xres=f32(y); xb=bf16(y) ----------------
__global__ __launch_bounds__(256) void ln_fused(const short* __restrict__ y1, const float* __restrict__ y2,
                                                const float* __restrict__ gg, const float* __restrict__ bb,
                                                float* __restrict__ xres, short* __restrict__ xb){
  const int row = blockIdx.x, tid = threadIdx.x;
  size_t base = (size_t)row*EE + tid*4;
  s4v a = *(const s4v*)(y1 + base);
  f4v c = *(const f4v*)(y2 + base);
  f4v y;
  #pragma unroll
  for (int j=0;j<4;j++) y[j] = b2f(a[j]) + c[j];
  float s  = y[0]+y[1]+y[2]+y[3];
  float sq = y[0]*y[0]+y[1]*y[1]+y[2]*y[2]+y[3]*y[3];
  #pragma unroll
  for (int msk=1; msk<64; msk<<=1){ s += __shfl_xor(s, msk); sq += __shfl_xor(sq, msk); }
  __shared__ float red[8];
  int wave = tid>>6;
  if ((tid&63)==0){ red[wave]=s; red[4+wave]=sq; }
  __syncthreads();
  s  = red[0]+red[1]+red[2]+red[3];
  sq = red[4]+red[5]+red[6]+red[7];
  float mu  = s * (1.f/EE);
  float var = sq * (1.f/EE) - mu*mu;
  float rstd = rsqrtf(var + 1e-5f);
  f4v ov; s4v ob;
  #pragma unroll
  for (int j=0;j<4;j++){
    int ccol = tid*4 + j;
    float v = (y[j]-mu)*rstd*gg[ccol] + bb[ccol];
    ov[j]=v; ob[j]=f2b(v);
  }
  *(f4v*)(xres + base) = ov;
  *(s4v*)(xb + base) = ob;
}

extern "C" void kernel_launch(void* const* d_in, const int* in_sizes, int n_in,
                              void* d_out, int out_size, void* d_ws, size_t ws_size,
                              hipStream_t stream){
  const float* x   = (const float*)d_in[0];
  const float* pe  = (const float*)d_in[1];
  const float* Wq  = (const float*)d_in[2];
  const float* bq  = (const float*)d_in[3];
  const float* Wk  = (const float*)d_in[4];
  const float* bk  = (const float*)d_in[5];
  const float* Wv  = (const float*)d_in[6];
  const float* bv  = (const float*)d_in[7];
  const float* Wo  = (const float*)d_in[8];
  const float* bo  = (const float*)d_in[9];
  const float* g1  = (const float*)d_in[10];
  const float* be1 = (const float*)d_in[11];
  const float* g2  = (const float*)d_in[12];
  const float* be2 = (const float*)d_in[13];
  const float* W1  = (const float*)d_in[14];
  const float* fb1 = (const float*)d_in[15];
  const float* W2  = (const float*)d_in[16];
  const float* fb2 = (const float*)d_in[17];

  // workspace layout (~80 MB)
  char* wsp = (char*)d_ws;
  float* xres = (float*)wsp;  wsp += (size_t)MM*EE*4;      // 16 MB
  short* xb   = (short*)wsp;  wsp += (size_t)MM*EE*2;      //  8 MB
  short* act  = (short*)wsp;  wsp += (size_t)MM*FF*2;      // 32 MB (qkv 24MB / hid 32MB share)
  short* ob   = (short*)wsp;  wsp += (size_t)MM*AA*2;      //  8 MB
  short* tmpb = (short*)wsp;  wsp += (size_t)MM*EE*2;      //  8 MB
  short* wT   = (short*)wsp;  wsp += (size_t)FF*EE*2;      //  8 MB (reused per-GEMM)
  float* bqkv = (float*)wsp;  wsp += 3*AA*4;
  short* qkv  = act;   // [M][3A]
  short* hid  = act;   // [M][F]

  add_pe_k<<<(MM*EE)/(256*4), 256, 0, stream>>>(x, pe, xres, xb);

  dim3 tb(32,8);
  for (int l=0; l<LL; l++){
    // --- QKV: transpose+convert weights into wT ([3A][E] bf16), fused projection ---
    transpose_f2b<<<dim3(DHD/32, EE/32, HH), tb, 0, stream>>>(Wq + (size_t)l*HH*EE*DHD, wT, EE, DHD);
    transpose_f2b<<<dim3(DHD/32, EE/32, HH), tb, 0, stream>>>(Wk + (size_t)l*HH*EE*DHD, wT + (size_t)AA*EE, EE, DHD);
    transpose_f2b<<<dim3(DHD/32, EE/32, HH), tb, 0, stream>>>(Wv + (size_t)l*HH*EE*DHD, wT + (size_t)2*AA*EE, EE, DHD);
    concat_bias<<<12, 256, 0, stream>>>(bq + l*AA, bk + l*AA, bv + l*AA, bqkv);
    gemm_bt<128,128,0><<<dim3(3*AA/128, MM/128), 256, 0, stream>>>(xb, wT, bqkv, qkv, MM, 3*AA, EE);
    // --- attention ---
    attn_k<<<dim3(SS/64, BB*HH), 256, 0, stream>>>(qkv, ob);
    // --- output projection ---
    transpose_f2b<<<dim3(EE/32, AA/32, 1), tb, 0, stream>>>(Wo + (size_t)l*AA*EE, wT, AA, EE);
    gemm_bt<64,128,0><<<dim3(EE/128, MM/64), 256, 0, stream>>>(ob, wT, bo + l*EE, tmpb, MM, EE, AA);
    ln_fused<<<MM, 256, 0, stream>>>(tmpb, xres, g1 + l*EE, be1 + l*EE, xres, xb);
    // --- FFN ---
    transpose_f2b<<<dim3(FF/32, EE/32, 1), tb, 0, stream>>>(W1 + (size_t)l*EE*FF, wT, EE, FF);
    gemm_bt<128,128,1><<<dim3(FF/128, MM/128), 256, 0, stream>>>(xb, wT, fb1 + l*FF, hid, MM, FF, EE);
    transpose_f2b<<<dim3(EE/32, FF/32, 1), tb, 0, stream>>>(W2 + (size_t)l*FF*EE, wT, FF, EE);
    gemm_bt<64,128,0><<<dim3(EE/128, MM/64), 256, 0, stream>>>(hid, wT, fb2 + l*EE, tmpb, MM, EE, FF);
    ln_fused<<<MM, 256, 0, stream>>>(tmpb, xres, g2 + l*EE, be2 + l*EE, xres, xb);
  }

  hipMemcpyAsync(d_out, xres, (size_t)MM*EE*4, hipMemcpyDeviceToDevice, stream);
}

// Round 4
// 1285.628 us; speedup vs baseline: 1.1615x; 1.1615x over previous
//
#include <hip/hip_runtime.h>

#define DEV __device__ __forceinline__

typedef __attribute__((ext_vector_type(8))) short s8v;
typedef __attribute__((ext_vector_type(4))) short s4v;
typedef __attribute__((ext_vector_type(4))) float f4v;

#define BB 2
#define SS 2048
#define EE 1024
#define AA 1024
#define HH 16
#define FF 4096
#define LL 4
#define DHD 64
#define MM (BB*SS)   /* 4096 rows */

DEV float b2f(short s){
  union { unsigned int u; float f; } v; v.u = ((unsigned int)(unsigned short)s) << 16; return v.f;
}
DEV short f2b(float f){
  unsigned int u = __float_as_uint(f);
  unsigned int r = (u + 0x7FFFu + ((u >> 16) & 1u)) >> 16;
  return (short)(unsigned short)r;
}
DEV void gld16(const void* g, void* l){
  __builtin_amdgcn_global_load_lds((const __attribute__((address_space(1))) unsigned int*)g,
                                   (__attribute__((address_space(3))) unsigned int*)l,
                                   16, 0, 0);
}
DEV f4v fzero(){ f4v v; v[0]=0.f; v[1]=0.f; v[2]=0.f; v[3]=0.f; return v; }
// XOR swizzle for [64][64] bf16 LDS tiles (short-index): spreads the 16-row
// column-slice read across 8 distinct 16B slots (b128 bank floor).
DEV int swz64(int row, int col){ return row*64 + (col ^ ((row&7)<<3)); }

// ---------------- add positional encoding: xres(f32) = x + pe ; xb = bf16 ----------------
__global__ __launch_bounds__(256) void add_pe_k(const float* __restrict__ x, const float* __restrict__ pe,
                                                float* __restrict__ xres, short* __restrict__ xb){
  size_t g = ((size_t)blockIdx.x*256 + threadIdx.x) * 4;
  f4v xv = *(const f4v*)(x + g);
  f4v pv = *(const f4v*)(pe + (g & (size_t)(SS*EE - 1)));
  f4v ov; s4v ob;
  #pragma unroll
  for (int j=0;j<4;j++){ float f = xv[j] + pv[j]; ov[j]=f; ob[j]=f2b(f); }
  *(f4v*)(xres + g) = ov;
  *(s4v*)(xb + g) = ob;
}

// ---------------- batched transpose+convert: in[z][R][C] (f32) -> out[z][C][R] (bf16) ----------------
__global__ __launch_bounds__(256) void transpose_f2b(const float* __restrict__ in, short* __restrict__ out,
                                                     int R, int C){
  __shared__ short t[32][33];
  int tx = threadIdx.x, ty = threadIdx.y;
  int rt = blockIdx.y*32, ct = blockIdx.x*32;
  size_t zb = (size_t)blockIdx.z * R * C;
  #pragma unroll
  for (int yy=0; yy<4; yy++){
    int iy = ty + yy*8;
    t[iy][tx] = f2b(in[zb + (size_t)(rt+iy)*C + ct + tx]);
  }
  __syncthreads();
  #pragma unroll
  for (int yy=0; yy<4; yy++){
    int iy = ty + yy*8;
    out[zb + (size_t)(ct+iy)*R + rt + tx] = t[tx][iy];
  }
}

// ---------------- V pre-transpose: qkv V-section [t][d] -> Vt[bh][d][t] (bf16) ----------------
__global__ __launch_bounds__(256) void vt_k(const short* __restrict__ qkv, short* __restrict__ Vt){
  __shared__ short t[32][33];
  int tx = threadIdx.x, ty = threadIdx.y;
  int t0 = blockIdx.x*32, d0 = blockIdx.y*32, bh = blockIdx.z;
  int b = bh >> 4, h = bh & 15;
  const short* src = qkv + (size_t)b*SS*3*AA + 2*AA + h*64;
  #pragma unroll
  for (int yy=0; yy<4; yy++){
    int iy = ty + yy*8;
    t[iy][tx] = src[(size_t)(t0+iy)*3*AA + d0 + tx];
  }
  __syncthreads();
  #pragma unroll
  for (int yy=0; yy<4; yy++){
    int iy = ty + yy*8;
    Vt[((size_t)bh*64 + d0 + iy)*SS + t0 + tx] = t[tx][iy];
  }
}

// ---------------- concat per-layer qkv biases into [3A] (f32) ----------------
__global__ void concat_bias(const float* __restrict__ bq, const float* __restrict__ bk,
                            const float* __restrict__ bv, float* __restrict__ out){
  int i = blockIdx.x*256 + threadIdx.x;
  float v = (i < AA) ? bq[i] : (i < 2*AA ? bk[i-AA] : bv[i-2*AA]);
  out[i] = v;
}

// ---------------- GEMM: C[M,N] = A[M,K](bf16) * Bt[N,K]^T + bias(f32) ----------------
// OUTMODE: 0 = bf16, 1 = bf16 + relu    (global_load_lds width-16 staging, m97 structure)
template<int BM, int BN, int OUTMODE>
__global__ __launch_bounds__(256) void gemm_bt(const short* __restrict__ Ag, const short* __restrict__ Btg,
                                               const float* __restrict__ bias, short* __restrict__ Cout,
                                               int M, int N, int K){
  constexpr int WM = BM/2, WN = BN/2;
  constexpr int MI = WM/16, NI = WN/16;
  constexpr int ACH = BM/16, BCH = BN/16, TCH = ACH + BCH, CPW = TCH/4;
  __shared__ __attribute__((aligned(16))) short As[BM*32];
  __shared__ __attribute__((aligned(16))) short Bs[BN*32];
  const int tid = threadIdx.x;
  const int wave = tid >> 6, lane = tid & 63;
  const int wr = wave >> 1, wc = wave & 1;
  const int l15 = lane & 15, l4 = lane >> 4;
  const int bm = blockIdx.y * BM, bn = blockIdx.x * BN;
  const int lrow = lane >> 2, lcol = (lane & 3) * 8;

  f4v acc[MI][NI];
  #pragma unroll
  for (int i=0;i<MI;i++)
    #pragma unroll
    for (int j=0;j<NI;j++) acc[i][j] = fzero();

  for (int kt = 0; kt < K; kt += 32){
    #pragma unroll
    for (int c = 0; c < CPW; c++){
      int ch = wave * CPW + c;
      if (ch < ACH){
        int r = ch*16 + lrow;
        gld16(Ag + (size_t)(bm + r)*K + kt + lcol, &As[ch*512]);
      } else {
        int r = (ch-ACH)*16 + lrow;
        gld16(Btg + (size_t)(bn + r)*K + kt + lcol, &Bs[(ch-ACH)*512]);
      }
    }
    __syncthreads();
    s8v af[MI], bfr[NI];
    #pragma unroll
    for (int mi=0;mi<MI;mi++) af[mi] = *(const s8v*)&As[(wr*WM + mi*16 + l15)*32 + l4*8];
    #pragma unroll
    for (int ni=0;ni<NI;ni++) bfr[ni] = *(const s8v*)&Bs[(wc*WN + ni*16 + l15)*32 + l4*8];
    #pragma unroll
    for (int mi=0;mi<MI;mi++)
      #pragma unroll
      for (int ni=0;ni<NI;ni++)
        acc[mi][ni] = __builtin_amdgcn_mfma_f32_16x16x32_bf16(af[mi], bfr[ni], acc[mi][ni], 0,0,0);
    __syncthreads();
  }
  #pragma unroll
  for (int mi=0;mi<MI;mi++){
    int row = bm + wr*WM + mi*16 + l4*4;
    #pragma unroll
    for (int ni=0;ni<NI;ni++){
      int col = bn + wc*WN + ni*16 + l15;
      float bv = bias[col];
      #pragma unroll
      for (int r=0;r<4;r++){
        float v = acc[mi][ni][r] + bv;
        if constexpr (OUTMODE==1) v = fmaxf(v, 0.f);
        Cout[(size_t)(row+r)*N + col] = f2b(v);
      }
    }
  }
}

// ---------------- flash attention (swapped QK^T, in-register softmax) ----------------
// S^T = mfma(K, Q): lane owns col m = l15, 16 t-values (f,r) in-register.
// PV: O^T = mfma(V^T, P^T) with V^T pre-transposed in Vt.
__global__ __launch_bounds__(256) void attn_k(const short* __restrict__ qkv, const short* __restrict__ Vt,
                                              short* __restrict__ o){
  __shared__ __attribute__((aligned(16))) short Kls[64*64];
  __shared__ __attribute__((aligned(16))) short Vls[64*64];
  __shared__ __attribute__((aligned(16))) short Pls[4][16][68];
  const int tid = threadIdx.x, wave = tid>>6, lane = tid&63;
  const int l15 = lane&15, l4 = lane>>4;
  const int qb = blockIdx.x, bh = blockIdx.y;
  const int b = bh >> 4, h = bh & 15;
  const size_t rs = 3*AA;
  const short* qbase = qkv + (size_t)b*SS*rs + h*64;
  const short* kbase = qbase + AA;
  const short* vtb   = Vt + (size_t)bh*64*SS;
  const int m0 = qb*64 + wave*16;

  // Q fragments (B-operand of swapped QK^T): lane l15 = m, octet l4 = d-chunk
  s8v aq0 = *(const s8v*)(qbase + (size_t)(m0 + l15)*rs + l4*8);
  s8v aq1 = *(const s8v*)(qbase + (size_t)(m0 + l15)*rs + 32 + l4*8);

  f4v oacc[4];   // O^T: [df block][r]: d = df*16 + l4*4 + r, col m = l15
  #pragma unroll
  for (int df=0;df<4;df++) oacc[df] = fzero();
  float mrow = -1e30f, lrow = 0.f;

  const int srow = tid >> 3, scol = (tid & 7) * 8;   // staging: 32 rows/pass, 2 passes
  for (int t0=0; t0<SS; t0+=64){
    // stage K tile [t][d] and V^T tile [d][t], both XOR-swizzled
    #pragma unroll
    for (int p=0; p<2; p++){
      int r = p*32 + srow;
      *(s8v*)&Kls[swz64(r, scol)] = *(const s8v*)(kbase + (size_t)(t0+r)*rs + scol);
      *(s8v*)&Vls[swz64(r, scol)] = *(const s8v*)(vtb + (size_t)r*SS + t0 + scol);
    }
    __syncthreads();

    // S^T[t][m]: 4 f-blocks of 16 t, K=64 via 2 chunks
    f4v sacc[4];
    #pragma unroll
    for (int f=0; f<4; f++){
      s8v k0 = *(const s8v*)&Kls[swz64(f*16+l15, l4*8)];
      s8v k1 = *(const s8v*)&Kls[swz64(f*16+l15, 32+l4*8)];
      f4v s = fzero();
      s = __builtin_amdgcn_mfma_f32_16x16x32_bf16(k0, aq0, s, 0,0,0);
      s = __builtin_amdgcn_mfma_f32_16x16x32_bf16(k1, aq1, s, 0,0,0);
      sacc[f] = s * 0.125f;
    }

    // in-register online softmax over t (lane has 16 of 64 t; 4 l4-lanes share col m)
    float mx = sacc[0][0];
    #pragma unroll
    for (int f=0; f<4; f++)
      #pragma unroll
      for (int r=0; r<4; r++) mx = fmaxf(mx, sacc[f][r]);
    mx = fmaxf(mx, __shfl_xor(mx, 16));
    mx = fmaxf(mx, __shfl_xor(mx, 32));
    float mnew = fmaxf(mrow, mx);
    float fc = __expf(mrow - mnew);
    float rsum = 0.f;
    #pragma unroll
    for (int f=0; f<4; f++){
      #pragma unroll
      for (int r=0; r<4; r++){
        float p = __expf(sacc[f][r] - mnew);
        sacc[f][r] = p; rsum += p;
      }
    }
    rsum += __shfl_xor(rsum, 16);
    rsum += __shfl_xor(rsum, 32);
    lrow = lrow*fc + rsum;
    mrow = mnew;
    #pragma unroll
    for (int df=0;df<4;df++) oacc[df] = oacc[df] * fc;

    // P^T -> LDS, packed b64 (t = 16f + 4*l4 + r, col m = l15)
    #pragma unroll
    for (int f=0; f<4; f++){
      s4v q;
      #pragma unroll
      for (int r=0; r<4; r++) q[r] = f2b(sacc[f][r]);
      *(s4v*)&Pls[wave][l15][f*16 + l4*4] = q;
    }

    // P^T fragments (B-operand of PV): lane l15 = m, octet l4 -> t chunk
    s8v ap0 = *(const s8v*)&Pls[wave][l15][l4*8];
    s8v ap1 = *(const s8v*)&Pls[wave][l15][32 + l4*8];
    #pragma unroll
    for (int df=0; df<4; df++){
      s8v v0 = *(const s8v*)&Vls[swz64(df*16+l15, l4*8)];
      s8v v1 = *(const s8v*)&Vls[swz64(df*16+l15, 32+l4*8)];
      oacc[df] = __builtin_amdgcn_mfma_f32_16x16x32_bf16(v0, ap0, oacc[df], 0,0,0);
      oacc[df] = __builtin_amdgcn_mfma_f32_16x16x32_bf16(v1, ap1, oacc[df], 0,0,0);
    }
    __syncthreads();
  }
  // O^T -> o[m][d]: lane col m = l15, rows d = df*16 + l4*4 + r (4 consecutive -> b64)
  float rl = 1.f / lrow;
  short* orow = o + (size_t)(b*SS + m0 + l15)*AA + h*64;
  #pragma unroll
  for (int df=0; df<4; df++){
    s4v q;
    #pragma unroll
    for (int r=0; r<4; r++) q[r] = f2b(oacc[df][r] * rl);
    *(s4v*)&orow[df*16 + l4*4] = q;
  }
}

// ---------------- fused residual + layernorm ----------------
__global__ __launch_bounds__(256) void ln_fused(const short* __restrict__ y1, const float* __restrict__ y2,
                                                const float* __restrict__ gg, const float* __restrict__ bb,
                                                float* __restrict__ xres, short* __restrict__ xb){
  const int row = blockIdx.x, tid = threadIdx.x;
  size_t base = (size_t)row*EE + tid*4;
  s4v a = *(const s4v*)(y1 + base);
  f4v c = *(const f4v*)(y2 + base);
  f4v y;
  #pragma unroll
  for (int j=0;j<4;j++) y[j] = b2f(a[j]) + c[j];
  float s  = y[0]+y[1]+y[2]+y[3];
  float sq = y[0]*y[0]+y[1]*y[1]+y[2]*y[2]+y[3]*y[3];
  #pragma unroll
  for (int msk=1; msk<64; msk<<=1){ s += __shfl_xor(s, msk); sq += __shfl_xor(sq, msk); }
  __shared__ float red[8];
  int wave = tid>>6;
  if ((tid&63)==0){ red[wave]=s; red[4+wave]=sq; }
  __syncthreads();
  s  = red[0]+red[1]+red[2]+red[3];
  sq = red[4]+red[5]+red[6]+red[7];
  float mu  = s * (1.f/EE);
  float var = sq * (1.f/EE) - mu*mu;
  float rstd = rsqrtf(var + 1e-5f);
  f4v ov; s4v ob;
  #pragma unroll
  for (int j=0;j<4;j++){
    int ccol = tid*4 + j;
    float v = (y[j]-mu)*rstd*gg[ccol] + bb[ccol];
    ov[j]=v; ob[j]=f2b(v);
  }
  *(f4v*)(xres + base) = ov;
  *(s4v*)(xb + base) = ob;
}

extern "C" void kernel_launch(void* const* d_in, const int* in_sizes, int n_in,
                              void* d_out, int out_size, void* d_ws, size_t ws_size,
                              hipStream_t stream){
  const float* x   = (const float*)d_in[0];
  const float* pe  = (const float*)d_in[1];
  const float* Wq  = (const float*)d_in[2];
  const float* bq  = (const float*)d_in[3];
  const float* Wk  = (const float*)d_in[4];
  const float* bk  = (const float*)d_in[5];
  const float* Wv  = (const float*)d_in[6];
  const float* bv  = (const float*)d_in[7];
  const float* Wo  = (const float*)d_in[8];
  const float* bo  = (const float*)d_in[9];
  const float* g1  = (const float*)d_in[10];
  const float* be1 = (const float*)d_in[11];
  const float* g2  = (const float*)d_in[12];
  const float* be2 = (const float*)d_in[13];
  const float* W1  = (const float*)d_in[14];
  const float* fb1 = (const float*)d_in[15];
  const float* W2  = (const float*)d_in[16];
  const float* fb2 = (const float*)d_in[17];

  // workspace layout (~80 MB)
  char* wsp = (char*)d_ws;
  float* xres = (float*)wsp;  wsp += (size_t)MM*EE*4;      // 16 MB
  short* xb   = (short*)wsp;  wsp += (size_t)MM*EE*2;      //  8 MB
  short* act  = (short*)wsp;  wsp += (size_t)MM*FF*2;      // 32 MB (qkv 24 + Vt 8 | hid 32)
  short* ob   = (short*)wsp;  wsp += (size_t)MM*AA*2;      //  8 MB
  short* tmpb = (short*)wsp;  wsp += (size_t)MM*EE*2;      //  8 MB
  short* wT   = (short*)wsp;  wsp += (size_t)FF*EE*2;      //  8 MB (reused per-GEMM)
  float* bqkv = (float*)wsp;  wsp += 3*AA*4;
  short* qkv  = act;                        // [M][3A]
  short* Vtb  = act + (size_t)MM*3*AA;      // [BH][64][SS]
  short* hid  = act;                        // [M][F] (FFN phase only)

  add_pe_k<<<(MM*EE)/(256*4), 256, 0, stream>>>(x, pe, xres, xb);

  dim3 tb(32,8);
  for (int l=0; l<LL; l++){
    // --- QKV projection ---
    transpose_f2b<<<dim3(DHD/32, EE/32, HH), tb, 0, stream>>>(Wq + (size_t)l*HH*EE*DHD, wT, EE, DHD);
    transpose_f2b<<<dim3(DHD/32, EE/32, HH), tb, 0, stream>>>(Wk + (size_t)l*HH*EE*DHD, wT + (size_t)AA*EE, EE, DHD);
    transpose_f2b<<<dim3(DHD/32, EE/32, HH), tb, 0, stream>>>(Wv + (size_t)l*HH*EE*DHD, wT + (size_t)2*AA*EE, EE, DHD);
    concat_bias<<<12, 256, 0, stream>>>(bq + l*AA, bk + l*AA, bv + l*AA, bqkv);
    gemm_bt<128,128,0><<<dim3(3*AA/128, MM/128), 256, 0, stream>>>(xb, wT, bqkv, qkv, MM, 3*AA, EE);
    // --- attention (V pre-transpose + flash) ---
    vt_k<<<dim3(SS/32, 2, BB*HH), tb, 0, stream>>>(qkv, Vtb);
    attn_k<<<dim3(SS/64, BB*HH), 256, 0, stream>>>(qkv, Vtb, ob);
    // --- output projection ---
    transpose_f2b<<<dim3(EE/32, AA/32, 1), tb, 0, stream>>>(Wo + (size_t)l*AA*EE, wT, AA, EE);
    gemm_bt<64,128,0><<<dim3(EE/128, MM/64), 256, 0, stream>>>(ob, wT, bo + l*EE, tmpb, MM, EE, AA);
    ln_fused<<<MM, 256, 0, stream>>>(tmpb, xres, g1 + l*EE, be1 + l*EE, xres, xb);
    // --- FFN ---
    transpose_f2b<<<dim3(FF/32, EE/32, 1), tb, 0, stream>>>(W1 + (size_t)l*EE*FF, wT, EE, FF);
    gemm_bt<128,128,1><<<dim3(FF/128, MM/128), 256, 0, stream>>>(xb, wT, fb1 + l*FF, hid, MM, FF, EE);
    transpose_f2b<<<dim3(EE/32, FF/32, 1), tb, 0, stream>>>(W2 + (size_t)l*FF*EE, wT, FF, EE);
    gemm_bt<64,128,0><<<dim3(EE/128, MM/64), 256, 0, stream>>>(hid, wT, fb2 + l*EE, tmpb, MM, EE, FF);
    ln_fused<<<MM, 256, 0, stream>>>(tmpb, xres, g2 + l*EE, be2 + l*EE, xres, xb);
  }

  hipMemcpyAsync(d_out, xres, (size_t)MM*EE*4, hipMemcpyDeviceToDevice, stream);
}

// Round 5
// 1185.703 us; speedup vs baseline: 1.2593x; 1.0843x over previous
//
#include <hip/hip_runtime.h>

#define DEV __device__ __forceinline__

typedef __attribute__((ext_vector_type(8))) short s8v;
typedef __attribute__((ext_vector_type(4))) short s4v;
typedef __attribute__((ext_vector_type(4))) float f4v;

#define BB 2
#define SS 2048
#define EE 1024
#define AA 1024
#define HH 16
#define FF 4096
#define LL 4
#define DHD 64
#define MM (BB*SS)   /* 4096 rows */

DEV float b2f(short s){
  union { unsigned int u; float f; } v; v.u = ((unsigned int)(unsigned short)s) << 16; return v.f;
}
DEV short f2b(float f){
  unsigned int u = __float_as_uint(f);
  unsigned int r = (u + 0x7FFFu + ((u >> 16) & 1u)) >> 16;
  return (short)(unsigned short)r;
}
DEV void gld16(const void* g, void* l){
  __builtin_amdgcn_global_load_lds((const __attribute__((address_space(1))) unsigned int*)g,
                                   (__attribute__((address_space(3))) unsigned int*)l,
                                   16, 0, 0);
}
DEV f4v fzero(){ f4v v; v[0]=0.f; v[1]=0.f; v[2]=0.f; v[3]=0.f; return v; }
// XOR swizzle for [64][64] bf16 LDS tiles (short-index), attention only.
DEV int swz64(int row, int col){ return row*64 + (col ^ ((row&7)<<3)); }

// ---------------- add positional encoding: xres(f32) = x + pe ; xb = bf16 ----------------
__global__ __launch_bounds__(256) void add_pe_k(const float* __restrict__ x, const float* __restrict__ pe,
                                                float* __restrict__ xres, short* __restrict__ xb){
  size_t g = ((size_t)blockIdx.x*256 + threadIdx.x) * 4;
  f4v xv = *(const f4v*)(x + g);
  f4v pv = *(const f4v*)(pe + (g & (size_t)(SS*EE - 1)));
  f4v ov; s4v ob;
  #pragma unroll
  for (int j=0;j<4;j++){ float f = xv[j] + pv[j]; ov[j]=f; ob[j]=f2b(f); }
  *(f4v*)(xres + g) = ov;
  *(s4v*)(xb + g) = ob;
}

// ---------------- batched transpose+convert: in[z][R][C] (f32) -> out[z][C][R] (bf16) ----------------
__global__ __launch_bounds__(256) void transpose_f2b(const float* __restrict__ in, short* __restrict__ out,
                                                     int R, int C){
  __shared__ short t[32][33];
  int tx = threadIdx.x, ty = threadIdx.y;
  int rt = blockIdx.y*32, ct = blockIdx.x*32;
  size_t zb = (size_t)blockIdx.z * R * C;
  #pragma unroll
  for (int yy=0; yy<4; yy++){
    int iy = ty + yy*8;
    t[iy][tx] = f2b(in[zb + (size_t)(rt+iy)*C + ct + tx]);
  }
  __syncthreads();
  #pragma unroll
  for (int yy=0; yy<4; yy++){
    int iy = ty + yy*8;
    out[zb + (size_t)(ct+iy)*R + rt + tx] = t[tx][iy];
  }
}

// ---------------- V pre-transpose: qkv V-section [t][d] -> Vt[bh][d][t] (bf16) ----------------
__global__ __launch_bounds__(256) void vt_k(const short* __restrict__ qkv, short* __restrict__ Vt){
  __shared__ short t[32][33];
  int tx = threadIdx.x, ty = threadIdx.y;
  int t0 = blockIdx.x*32, d0 = blockIdx.y*32, bh = blockIdx.z;
  int b = bh >> 4, h = bh & 15;
  const short* src = qkv + (size_t)b*SS*3*AA + 2*AA + h*64;
  #pragma unroll
  for (int yy=0; yy<4; yy++){
    int iy = ty + yy*8;
    t[iy][tx] = src[(size_t)(t0+iy)*3*AA + d0 + tx];
  }
  __syncthreads();
  #pragma unroll
  for (int yy=0; yy<4; yy++){
    int iy = ty + yy*8;
    Vt[((size_t)bh*64 + d0 + iy)*SS + t0 + tx] = t[tx][iy];
  }
}

// ---------------- concat per-layer qkv biases into [3A] (f32) ----------------
__global__ void concat_bias(const float* __restrict__ bq, const float* __restrict__ bk,
                            const float* __restrict__ bv, float* __restrict__ out){
  int i = blockIdx.x*256 + threadIdx.x;
  float v = (i < AA) ? bq[i] : (i < 2*AA ? bk[i-AA] : bv[i-2*AA]);
  out[i] = v;
}

// ---------------- GEMM: C[M,N] = A[M,K](bf16) * Bt[N,K]^T + bias(f32) ----------------
// OUTMODE: 0 = bf16, 1 = bf16 + relu
// Double-buffered 2-phase K-loop (T3-minimum) + XCD-aware bijective block remap (T1).
template<int BM, int BN, int OUTMODE>
__global__ __launch_bounds__(256) void gemm_bt(const short* __restrict__ Ag, const short* __restrict__ Btg,
                                               const float* __restrict__ bias, short* __restrict__ Cout,
                                               int M, int N, int K){
  constexpr int WM = BM/2, WN = BN/2;
  constexpr int MI = WM/16, NI = WN/16;
  constexpr int ACH = BM/16, BCH = BN/16, TCH = ACH + BCH, CPW = TCH/4;
  __shared__ __attribute__((aligned(16))) short As[2][BM*32];
  __shared__ __attribute__((aligned(16))) short Bs[2][BN*32];
  const int tid = threadIdx.x;
  const int wave = tid >> 6, lane = tid & 63;
  const int wr = wave >> 1, wc = wave & 1;
  const int l15 = lane & 15, l4 = lane >> 4;

  // T1: XCD-aware bijective remap of the linear block id (8 XCDs)
  const int gx = gridDim.x;
  const int nwg = gx * gridDim.y;
  const int w0 = blockIdx.y * gx + blockIdx.x;
  const int q8 = nwg >> 3, r8 = nwg & 7;
  const int xcd = w0 & 7, pos = w0 >> 3;
  const int lg = (xcd < r8 ? xcd*(q8+1) : r8*(q8+1) + (xcd-r8)*q8) + pos;
  const int bn = (lg % gx) * BN, bm = (lg / gx) * BM;

  const int lrow = lane >> 2, lcol = (lane & 3) * 8;

  f4v acc[MI][NI];
  #pragma unroll
  for (int i=0;i<MI;i++)
    #pragma unroll
    for (int j=0;j<NI;j++) acc[i][j] = fzero();

  // STAGE tile (kt) into buffer pb: global_load_lds width-16, wave-uniform LDS base
#define STAGE_TILE(pb, kt) \
  { _Pragma("unroll") \
    for (int c = 0; c < CPW; c++){ \
      int ch = wave * CPW + c; \
      if (ch < ACH){ \
        gld16(Ag + (size_t)(bm + ch*16 + lrow)*K + (kt) + lcol, &As[pb][ch*512]); \
      } else { \
        gld16(Btg + (size_t)(bn + (ch-ACH)*16 + lrow)*K + (kt) + lcol, &Bs[pb][(ch-ACH)*512]); \
      } \
    } }

#define COMPUTE_TILE(pb) \
  { s8v af[MI], bfr[NI]; \
    _Pragma("unroll") \
    for (int mi=0;mi<MI;mi++) af[mi] = *(const s8v*)&As[pb][(wr*WM + mi*16 + l15)*32 + l4*8]; \
    _Pragma("unroll") \
    for (int ni=0;ni<NI;ni++) bfr[ni] = *(const s8v*)&Bs[pb][(wc*WN + ni*16 + l15)*32 + l4*8]; \
    _Pragma("unroll") \
    for (int mi=0;mi<MI;mi++) \
      _Pragma("unroll") \
      for (int ni=0;ni<NI;ni++) \
        acc[mi][ni] = __builtin_amdgcn_mfma_f32_16x16x32_bf16(af[mi], bfr[ni], acc[mi][ni], 0,0,0); }

  // prologue: stage tile 0, wait (syncthreads drains vmcnt), then pipeline
  STAGE_TILE(0, 0);
  __syncthreads();
  int cur = 0;
  for (int kt = 32; kt < K; kt += 32){
    STAGE_TILE(cur^1, kt);     // issue next-tile loads (in flight during MFMA)
    COMPUTE_TILE(cur);         // ds_read frags + 16*MI*NI/16 MFMA
    __syncthreads();           // drains vmcnt(0): staged tile landed; all reads done
    cur ^= 1;
  }
  COMPUTE_TILE(cur);           // epilogue tile (no prefetch)

#undef STAGE_TILE
#undef COMPUTE_TILE

  #pragma unroll
  for (int mi=0;mi<MI;mi++){
    int row = bm + wr*WM + mi*16 + l4*4;
    #pragma unroll
    for (int ni=0;ni<NI;ni++){
      int col = bn + wc*WN + ni*16 + l15;
      float bv = bias[col];
      #pragma unroll
      for (int r=0;r<4;r++){
        float v = acc[mi][ni][r] + bv;
        if constexpr (OUTMODE==1) v = fmaxf(v, 0.f);
        Cout[(size_t)(row+r)*N + col] = f2b(v);
      }
    }
  }
}

// ---------------- flash attention (swapped QK^T, in-register softmax) ----------------
// S^T = mfma(K, Q): lane owns col m = l15, 16 t-values (f,r) in-register.
// PV: O^T = mfma(V^T, P^T) with V^T pre-transposed in Vt.
__global__ __launch_bounds__(256) void attn_k(const short* __restrict__ qkv, const short* __restrict__ Vt,
                                              short* __restrict__ o){
  __shared__ __attribute__((aligned(16))) short Kls[64*64];
  __shared__ __attribute__((aligned(16))) short Vls[64*64];
  __shared__ __attribute__((aligned(16))) short Pls[4][16][68];
  const int tid = threadIdx.x, wave = tid>>6, lane = tid&63;
  const int l15 = lane&15, l4 = lane>>4;
  const int qb = blockIdx.x, bh = blockIdx.y;
  const int b = bh >> 4, h = bh & 15;
  const size_t rs = 3*AA;
  const short* qbase = qkv + (size_t)b*SS*rs + h*64;
  const short* kbase = qbase + AA;
  const short* vtb   = Vt + (size_t)bh*64*SS;
  const int m0 = qb*64 + wave*16;

  // Q fragments (B-operand of swapped QK^T): lane l15 = m, octet l4 = d-chunk
  s8v aq0 = *(const s8v*)(qbase + (size_t)(m0 + l15)*rs + l4*8);
  s8v aq1 = *(const s8v*)(qbase + (size_t)(m0 + l15)*rs + 32 + l4*8);

  f4v oacc[4];   // O^T: [df block][r]: d = df*16 + l4*4 + r, col m = l15
  #pragma unroll
  for (int df=0;df<4;df++) oacc[df] = fzero();
  float mrow = -1e30f, lrow = 0.f;

  const int srow = tid >> 3, scol = (tid & 7) * 8;   // staging: 32 rows/pass, 2 passes
  for (int t0=0; t0<SS; t0+=64){
    // stage K tile [t][d] and V^T tile [d][t], both XOR-swizzled
    #pragma unroll
    for (int p=0; p<2; p++){
      int r = p*32 + srow;
      *(s8v*)&Kls[swz64(r, scol)] = *(const s8v*)(kbase + (size_t)(t0+r)*rs + scol);
      *(s8v*)&Vls[swz64(r, scol)] = *(const s8v*)(vtb + (size_t)r*SS + t0 + scol);
    }
    __syncthreads();

    // S^T[t][m]: 4 f-blocks of 16 t, K=64 via 2 chunks
    f4v sacc[4];
    #pragma unroll
    for (int f=0; f<4; f++){
      s8v k0 = *(const s8v*)&Kls[swz64(f*16+l15, l4*8)];
      s8v k1 = *(const s8v*)&Kls[swz64(f*16+l15, 32+l4*8)];
      f4v s = fzero();
      s = __builtin_amdgcn_mfma_f32_16x16x32_bf16(k0, aq0, s, 0,0,0);
      s = __builtin_amdgcn_mfma_f32_16x16x32_bf16(k1, aq1, s, 0,0,0);
      sacc[f] = s * 0.125f;
    }

    // in-register online softmax over t (lane has 16 of 64 t; 4 l4-lanes share col m)
    float mx = sacc[0][0];
    #pragma unroll
    for (int f=0; f<4; f++)
      #pragma unroll
      for (int r=0; r<4; r++) mx = fmaxf(mx, sacc[f][r]);
    mx = fmaxf(mx, __shfl_xor(mx, 16));
    mx = fmaxf(mx, __shfl_xor(mx, 32));
    float mnew = fmaxf(mrow, mx);
    float fc = __expf(mrow - mnew);
    float rsum = 0.f;
    #pragma unroll
    for (int f=0; f<4; f++){
      #pragma unroll
      for (int r=0; r<4; r++){
        float p = __expf(sacc[f][r] - mnew);
        sacc[f][r] = p; rsum += p;
      }
    }
    rsum += __shfl_xor(rsum, 16);
    rsum += __shfl_xor(rsum, 32);
    lrow = lrow*fc + rsum;
    mrow = mnew;
    #pragma unroll
    for (int df=0;df<4;df++) oacc[df] = oacc[df] * fc;

    // P^T -> LDS, packed b64 (t = 16f + 4*l4 + r, col m = l15)
    #pragma unroll
    for (int f=0; f<4; f++){
      s4v q;
      #pragma unroll
      for (int r=0; r<4; r++) q[r] = f2b(sacc[f][r]);
      *(s4v*)&Pls[wave][l15][f*16 + l4*4] = q;
    }

    // P^T fragments (B-operand of PV): lane l15 = m, octet l4 -> t chunk
    s8v ap0 = *(const s8v*)&Pls[wave][l15][l4*8];
    s8v ap1 = *(const s8v*)&Pls[wave][l15][32 + l4*8];
    #pragma unroll
    for (int df=0; df<4; df++){
      s8v v0 = *(const s8v*)&Vls[swz64(df*16+l15, l4*8)];
      s8v v1 = *(const s8v*)&Vls[swz64(df*16+l15, 32+l4*8)];
      oacc[df] = __builtin_amdgcn_mfma_f32_16x16x32_bf16(v0, ap0, oacc[df], 0,0,0);
      oacc[df] = __builtin_amdgcn_mfma_f32_16x16x32_bf16(v1, ap1, oacc[df], 0,0,0);
    }
    __syncthreads();
  }
  // O^T -> o[m][d]: lane col m = l15, rows d = df*16 + l4*4 + r (4 consecutive -> b64)
  float rl = 1.f / lrow;
  short* orow = o + (size_t)(b*SS + m0 + l15)*AA + h*64;
  #pragma unroll
  for (int df=0; df<4; df++){
    s4v q;
    #pragma unroll
    for (int r=0; r<4; r++) q[r] = f2b(oacc[df][r] * rl);
    *(s4v*)&orow[df*16 + l4*4] = q;
  }
}

// ---------------- fused residual + layernorm ----------------
__global__ __launch_bounds__(256) void ln_fused(const short* __restrict__ y1, const float* __restrict__ y2,
                                                const float* __restrict__ gg, const float* __restrict__ bb,
                                                float* __restrict__ xres, short* __restrict__ xb){
  const int row = blockIdx.x, tid = threadIdx.x;
  size_t base = (size_t)row*EE + tid*4;
  s4v a = *(const s4v*)(y1 + base);
  f4v c = *(const f4v*)(y2 + base);
  f4v y;
  #pragma unroll
  for (int j=0;j<4;j++) y[j] = b2f(a[j]) + c[j];
  float s  = y[0]+y[1]+y[2]+y[3];
  float sq = y[0]*y[0]+y[1]*y[1]+y[2]*y[2]+y[3]*y[3];
  #pragma unroll
  for (int msk=1; msk<64; msk<<=1){ s += __shfl_xor(s, msk); sq += __shfl_xor(sq, msk); }
  __shared__ float red[8];
  int wave = tid>>6;
  if ((tid&63)==0){ red[wave]=s; red[4+wave]=sq; }
  __syncthreads();
  s  = red[0]+red[1]+red[2]+red[3];
  sq = red[4]+red[5]+red[6]+red[7];
  float mu  = s * (1.f/EE);
  float var = sq * (1.f/EE) - mu*mu;
  float rstd = rsqrtf(var + 1e-5f);
  f4v ov; s4v ob;
  #pragma unroll
  for (int j=0;j<4;j++){
    int ccol = tid*4 + j;
    float v = (y[j]-mu)*rstd*gg[ccol] + bb[ccol];
    ov[j]=v; ob[j]=f2b(v);
  }
  *(f4v*)(xres + base) = ov;
  *(s4v*)(xb + base) = ob;
}

extern "C" void kernel_launch(void* const* d_in, const int* in_sizes, int n_in,
                              void* d_out, int out_size, void* d_ws, size_t ws_size,
                              hipStream_t stream){
  const float* x   = (const float*)d_in[0];
  const float* pe  = (const float*)d_in[1];
  const float* Wq  = (const float*)d_in[2];
  const float* bq  = (const float*)d_in[3];
  const float* Wk  = (const float*)d_in[4];
  const float* bk  = (const float*)d_in[5];
  const float* Wv  = (const float*)d_in[6];
  const float* bv  = (const float*)d_in[7];
  const float* Wo  = (const float*)d_in[8];
  const float* bo  = (const float*)d_in[9];
  const float* g1  = (const float*)d_in[10];
  const float* be1 = (const float*)d_in[11];
  const float* g2  = (const float*)d_in[12];
  const float* be2 = (const float*)d_in[13];
  const float* W1  = (const float*)d_in[14];
  const float* fb1 = (const float*)d_in[15];
  const float* W2  = (const float*)d_in[16];
  const float* fb2 = (const float*)d_in[17];

  // workspace layout (~80 MB)
  char* wsp = (char*)d_ws;
  float* xres = (float*)wsp;  wsp += (size_t)MM*EE*4;      // 16 MB
  short* xb   = (short*)wsp;  wsp += (size_t)MM*EE*2;      //  8 MB
  short* act  = (short*)wsp;  wsp += (size_t)MM*FF*2;      // 32 MB (qkv 24 + Vt 8 | hid 32)
  short* ob   = (short*)wsp;  wsp += (size_t)MM*AA*2;      //  8 MB
  short* tmpb = (short*)wsp;  wsp += (size_t)MM*EE*2;      //  8 MB
  short* wT   = (short*)wsp;  wsp += (size_t)FF*EE*2;      //  8 MB (reused per-GEMM)
  float* bqkv = (float*)wsp;  wsp += 3*AA*4;
  short* qkv  = act;                        // [M][3A]
  short* Vtb  = act + (size_t)MM*3*AA;      // [BH][64][SS]
  short* hid  = act;                        // [M][F] (FFN phase only)

  add_pe_k<<<(MM*EE)/(256*4), 256, 0, stream>>>(x, pe, xres, xb);

  dim3 tb(32,8);
  for (int l=0; l<LL; l++){
    // --- QKV projection ---
    transpose_f2b<<<dim3(DHD/32, EE/32, HH), tb, 0, stream>>>(Wq + (size_t)l*HH*EE*DHD, wT, EE, DHD);
    transpose_f2b<<<dim3(DHD/32, EE/32, HH), tb, 0, stream>>>(Wk + (size_t)l*HH*EE*DHD, wT + (size_t)AA*EE, EE, DHD);
    transpose_f2b<<<dim3(DHD/32, EE/32, HH), tb, 0, stream>>>(Wv + (size_t)l*HH*EE*DHD, wT + (size_t)2*AA*EE, EE, DHD);
    concat_bias<<<12, 256, 0, stream>>>(bq + l*AA, bk + l*AA, bv + l*AA, bqkv);
    gemm_bt<128,128,0><<<dim3(3*AA/128, MM/128), 256, 0, stream>>>(xb, wT, bqkv, qkv, MM, 3*AA, EE);
    // --- attention (V pre-transpose + flash) ---
    vt_k<<<dim3(SS/32, 2, BB*HH), tb, 0, stream>>>(qkv, Vtb);
    attn_k<<<dim3(SS/64, BB*HH), 256, 0, stream>>>(qkv, Vtb, ob);
    // --- output projection ---
    transpose_f2b<<<dim3(EE/32, AA/32, 1), tb, 0, stream>>>(Wo + (size_t)l*AA*EE, wT, AA, EE);
    gemm_bt<64,128,0><<<dim3(EE/128, MM/64), 256, 0, stream>>>(ob, wT, bo + l*EE, tmpb, MM, EE, AA);
    ln_fused<<<MM, 256, 0, stream>>>(tmpb, xres, g1 + l*EE, be1 + l*EE, xres, xb);
    // --- FFN ---
    transpose_f2b<<<dim3(FF/32, EE/32, 1), tb, 0, stream>>>(W1 + (size_t)l*EE*FF, wT, EE, FF);
    gemm_bt<128,128,1><<<dim3(FF/128, MM/128), 256, 0, stream>>>(xb, wT, fb1 + l*FF, hid, MM, FF, EE);
    transpose_f2b<<<dim3(EE/32, FF/32, 1), tb, 0, stream>>>(W2 + (size_t)l*FF*EE, wT, FF, EE);
    gemm_bt<64,128,0><<<dim3(EE/128, MM/64), 256, 0, stream>>>(hid, wT, fb2 + l*EE, tmpb, MM, EE, FF);
    ln_fused<<<MM, 256, 0, stream>>>(tmpb, xres, g2 + l*EE, be2 + l*EE, xres, xb);
  }

  hipMemcpyAsync(d_out, xres, (size_t)MM*EE*4, hipMemcpyDeviceToDevice, stream);
}